// Round 2
// baseline (71.154 us; speedup 1.0000x reference)
//
#include <hip/hip_runtime.h>
#include <hip/hip_bf16.h>

#define DN 128
#define DE 64
#define NN 512

typedef __bf16 bf16x8 __attribute__((ext_vector_type(8)));
typedef float  f32x4  __attribute__((ext_vector_type(4)));

// -------- fused prep ---------------------------------------------------------
// blocks 0..1023: rms_norm(nodes)*g_node -> rp = nn@Wr + b, cp = nn@Wc
// block 1024:     pack g_edge[k]*We[k][col] into bf16 MFMA fragment order
//                 frag f = kh*4 + ct; lane l elem e: k = kh*32+(l>>4)*8+e,
//                 col = ct*16+(l&15)
__global__ void prep_kernel(const float* __restrict__ nodes,
                            const float* __restrict__ g_node,
                            const float* __restrict__ g_edge,
                            const float* __restrict__ W,
                            const float* __restrict__ bias,
                            float* __restrict__ rp, float* __restrict__ cp,
                            __bf16* __restrict__ weg) {
    const int l = threadIdx.x;  // 0..63
    if (blockIdx.x == 1024) {
        for (int kh = 0; kh < 2; ++kh)
            for (int ct = 0; ct < 4; ++ct) {
                const int f = kh * 4 + ct;
                #pragma unroll
                for (int e = 0; e < 8; ++e) {
                    const int k   = kh * 32 + (l >> 4) * 8 + e;
                    const int col = ct * 16 + (l & 15);
                    weg[(f * 64 + l) * 8 + e] =
                        (__bf16)(g_edge[k] * W[(2 * DN + k) * DE + col]);
                }
            }
        return;
    }
    const int row = blockIdx.x;      // b*N + i
    __shared__ float nn[DN];

    float x0 = nodes[row * DN + l];
    float x1 = nodes[row * DN + l + 64];
    float ssq = x0 * x0 + x1 * x1;
    #pragma unroll
    for (int m = 1; m < 64; m <<= 1) ssq += __shfl_xor(ssq, m, 64);
    float scale = rsqrtf(ssq * (1.0f / DN) + 1.1920929e-7f);
    nn[l]      = x0 * scale * g_node[l];
    nn[l + 64] = x1 * scale * g_node[l + 64];
    __syncthreads();

    float accr = bias[l];
    float accc = 0.0f;
    #pragma unroll 4
    for (int d = 0; d < DN; ++d) {
        float nd = nn[d];
        accr += nd * W[d * DE + l];          // Wr = W[0:128]
        accc += nd * W[(DN + d) * DE + l];   // Wc = W[128:256]
    }
    rp[row * DE + l] = accr;
    cp[row * DE + l] = accc;
}

// -------- main: out^tile = (WeG)^T x^T  (D: row=e, col=j) -------------------
// block = 256 (4 waves); each wave: 4 M-tiles of 16 edge-rows along j.
// lane l: r16 = l&15 -> j offset within tile; kg = l>>4 -> k-group AND e-quad.
__global__ __launch_bounds__(256) void main_kernel(
    const float* __restrict__ edges, const float* __restrict__ rp,
    const float* __restrict__ cp, const __bf16* __restrict__ weg,
    float* __restrict__ out) {
    const int bid  = blockIdx.x;       // 0..2047
    const int row  = bid >> 1;         // b*N + i
    const int jblk = bid & 1;
    const int w    = threadIdx.x >> 6;
    const int l    = threadIdx.x & 63;
    const int jw   = jblk * 256 + w * 64;   // wave's j base; tiles at jw + t*16

    // whole (g_edge-scaled) We in registers: 8 frags x 4 VGPR
    bf16x8 wf[8];
    #pragma unroll
    for (int f = 0; f < 8; ++f)
        wf[f] = *reinterpret_cast<const bf16x8*>(weg + (f * 64 + l) * 8);

    const int r16 = l & 15;   // j offset within tile (D col)
    const int kg  = l >> 4;   // k-group; also e-quad (D rows kg*4..kg*4+3)

    // rp for this lane's 16 output cols: c*16 + kg*4 + 0..3
    f32x4 rpv[4];
    #pragma unroll
    for (int c = 0; c < 4; ++c)
        rpv[c] = *reinterpret_cast<const f32x4*>(rp + row * DE + c * 16 + kg * 4);

    const int bN = (row / NN) * NN;   // b*512 (base row of cp)

    #pragma unroll
    for (int t = 0; t < 4; ++t) {
        const int jt = jw + t * 16;
        const int j  = jt + r16;      // this lane's edge row (j index)
        const float* ep = edges + ((size_t)row * NN + j) * DE + kg * 8;
        f32x4 x0a = *reinterpret_cast<const f32x4*>(ep);
        f32x4 x0b = *reinterpret_cast<const f32x4*>(ep + 4);
        f32x4 x1a = *reinterpret_cast<const f32x4*>(ep + 32);
        f32x4 x1b = *reinterpret_cast<const f32x4*>(ep + 36);

        float ssq = 0.0f;
        #pragma unroll
        for (int e = 0; e < 4; ++e)
            ssq += x0a[e] * x0a[e] + x0b[e] * x0b[e]
                 + x1a[e] * x1a[e] + x1b[e] * x1b[e];
        ssq += __shfl_xor(ssq, 16, 64);
        ssq += __shfl_xor(ssq, 32, 64);
        const float scale = rsqrtf(ssq * (1.0f / DE) + 1.1920929e-7f);
        // every lane now holds the rms scale for ITS OWN row j — no epilogue shfl

        // raw x -> bf16 B-fragments (rms scale folded into epilogue)
        bf16x8 a0, a1;
        #pragma unroll
        for (int e = 0; e < 4; ++e) {
            a0[e]     = (__bf16)x0a[e];
            a0[e + 4] = (__bf16)x0b[e];
            a1[e]     = (__bf16)x1a[e];
            a1[e + 4] = (__bf16)x1b[e];
        }

        const float* cprow = cp  + (size_t)(bN + j) * DE + kg * 4;
        float*       orow  = out + ((size_t)row * NN + j) * DE + kg * 4;

        #pragma unroll
        for (int c = 0; c < 4; ++c) {
            f32x4 z = {0.f, 0.f, 0.f, 0.f};
            // A = (We*g)^T tile c, B = x^T  ->  D[m=e, n=j]
            z = __builtin_amdgcn_mfma_f32_16x16x32_bf16(wf[c],     a0, z, 0, 0, 0);
            z = __builtin_amdgcn_mfma_f32_16x16x32_bf16(wf[4 + c], a1, z, 0, 0, 0);

            f32x4 cp4 = *reinterpret_cast<const f32x4*>(cprow + c * 16);
            f32x4 o;
            #pragma unroll
            for (int r = 0; r < 4; ++r)
                o[r] = z[r] * scale + rpv[c][r] + cp4[r];
            *reinterpret_cast<f32x4*>(orow + c * 16) = o;
        }
    }
}

extern "C" void kernel_launch(void* const* d_in, const int* in_sizes, int n_in,
                              void* d_out, int out_size, void* d_ws, size_t ws_size,
                              hipStream_t stream) {
    const float* edges  = (const float*)d_in[0];
    const float* nodes  = (const float*)d_in[1];
    const float* g_node = (const float*)d_in[2];
    const float* g_edge = (const float*)d_in[3];
    const float* W      = (const float*)d_in[4];
    const float* bias   = (const float*)d_in[5];
    float* out = (float*)d_out;

    float*  rp  = (float*)d_ws;                 // 1024*64 f32 = 256 KB
    float*  cp  = rp + 1024 * DE;               // 256 KB
    __bf16* weg = (__bf16*)(cp + 1024 * DE);    // 8*64*8 bf16 = 8 KB

    prep_kernel<<<dim3(1025), dim3(64), 0, stream>>>(nodes, g_node, g_edge, W,
                                                     bias, rp, cp, weg);
    main_kernel<<<dim3(2048), dim3(256), 0, stream>>>(edges, rp, cp, weg, out);
}

// Round 3
// 69.362 us; speedup vs baseline: 1.0258x; 1.0258x over previous
//
#include <hip/hip_runtime.h>
#include <hip/hip_bf16.h>

#define DN 128
#define DE 64
#define NN 512

typedef __bf16 bf16x8 __attribute__((ext_vector_type(8)));
typedef float  f32x4  __attribute__((ext_vector_type(4)));

// -------- fused prep ---------------------------------------------------------
// blocks 0..1023: rms_norm(nodes)*g_node -> rp = nn@Wr + b, cp = nn@Wc
// block 1024:     pack g_edge[k]*We[k][col] into bf16 MFMA fragment order
__global__ void prep_kernel(const float* __restrict__ nodes,
                            const float* __restrict__ g_node,
                            const float* __restrict__ g_edge,
                            const float* __restrict__ W,
                            const float* __restrict__ bias,
                            float* __restrict__ rp, float* __restrict__ cp,
                            __bf16* __restrict__ weg) {
    const int l = threadIdx.x;  // 0..63
    if (blockIdx.x == 1024) {
        for (int kh = 0; kh < 2; ++kh)
            for (int ct = 0; ct < 4; ++ct) {
                const int f = kh * 4 + ct;
                #pragma unroll
                for (int e = 0; e < 8; ++e) {
                    const int k   = kh * 32 + (l >> 4) * 8 + e;
                    const int col = ct * 16 + (l & 15);
                    weg[(f * 64 + l) * 8 + e] =
                        (__bf16)(g_edge[k] * W[(2 * DN + k) * DE + col]);
                }
            }
        return;
    }
    const int row = blockIdx.x;      // b*N + i
    __shared__ float nn[DN];

    float x0 = nodes[row * DN + l];
    float x1 = nodes[row * DN + l + 64];
    float ssq = x0 * x0 + x1 * x1;
    #pragma unroll
    for (int m = 1; m < 64; m <<= 1) ssq += __shfl_xor(ssq, m, 64);
    float scale = rsqrtf(ssq * (1.0f / DN) + 1.1920929e-7f);
    nn[l]      = x0 * scale * g_node[l];
    nn[l + 64] = x1 * scale * g_node[l + 64];
    __syncthreads();

    float accr = bias[l];
    float accc = 0.0f;
    #pragma unroll 4
    for (int d = 0; d < DN; ++d) {
        float nd = nn[d];
        accr += nd * W[d * DE + l];          // Wr = W[0:128]
        accc += nd * W[(DN + d) * DE + l];   // Wc = W[128:256]
    }
    rp[row * DE + l] = accr;
    cp[row * DE + l] = accc;
}

// -------- main: ONE 16x16 j-tile per wave, all loads issued up-front --------
// grid 8192 x 256. bid: row = bid>>3, j-chunk = (bid&7)*64; wave w -> +w*16.
// lane l: r16 = l&15 -> j within tile; kg = l>>4 -> k-group / e-quad.
// out^tile = (We*g)^T x^T via mfma(wf, x): D[m=e, n=j]; rms scale folded
// into epilogue (lane owns its row's scale after 2 shfl_xor — no extra shfl).
__global__ __launch_bounds__(256) void main_kernel(
    const float* __restrict__ edges, const float* __restrict__ rp,
    const float* __restrict__ cp, const __bf16* __restrict__ weg,
    float* __restrict__ out) {
    const int bid  = blockIdx.x;       // 0..8191
    const int row  = bid >> 3;         // b*N + i
    const int w    = threadIdx.x >> 6;
    const int l    = threadIdx.x & 63;
    const int r16  = l & 15;
    const int kg   = l >> 4;
    const int jt   = (bid & 7) * 64 + w * 16;
    const int j    = jt + r16;         // this lane's edge row (j)
    const int bN   = (row >> 9) << 9;  // b*512

    // ---- issue ALL loads before any use: 20 independent VMEM ops ----
    const float* ep = edges + ((size_t)row * NN + j) * DE + kg * 8;
    f32x4 x0a = *reinterpret_cast<const f32x4*>(ep);
    f32x4 x0b = *reinterpret_cast<const f32x4*>(ep + 4);
    f32x4 x1a = *reinterpret_cast<const f32x4*>(ep + 32);
    f32x4 x1b = *reinterpret_cast<const f32x4*>(ep + 36);

    bf16x8 wf[8];
    #pragma unroll
    for (int f = 0; f < 8; ++f)
        wf[f] = *reinterpret_cast<const bf16x8*>(weg + (f * 64 + l) * 8);

    const float* cprow = cp + (size_t)(bN + j) * DE + kg * 4;
    f32x4 cpv[4];
    #pragma unroll
    for (int c = 0; c < 4; ++c)
        cpv[c] = *reinterpret_cast<const f32x4*>(cprow + c * 16);

    f32x4 rpv[4];
    #pragma unroll
    for (int c = 0; c < 4; ++c)
        rpv[c] = *reinterpret_cast<const f32x4*>(rp + row * DE + c * 16 + kg * 4);

    // ---- rms over this lane's row (64 floats split across lanes l, l^16, l^32) ----
    float ssq = 0.0f;
    #pragma unroll
    for (int e = 0; e < 4; ++e)
        ssq += x0a[e] * x0a[e] + x0b[e] * x0b[e]
             + x1a[e] * x1a[e] + x1b[e] * x1b[e];
    ssq += __shfl_xor(ssq, 16, 64);
    ssq += __shfl_xor(ssq, 32, 64);
    const float scale = rsqrtf(ssq * (1.0f / DE) + 1.1920929e-7f);

    bf16x8 a0, a1;
    #pragma unroll
    for (int e = 0; e < 4; ++e) {
        a0[e]     = (__bf16)x0a[e];
        a0[e + 4] = (__bf16)x0b[e];
        a1[e]     = (__bf16)x1a[e];
        a1[e + 4] = (__bf16)x1b[e];
    }

    float* orow = out + ((size_t)row * NN + j) * DE + kg * 4;
    #pragma unroll
    for (int c = 0; c < 4; ++c) {
        f32x4 z = {0.f, 0.f, 0.f, 0.f};
        z = __builtin_amdgcn_mfma_f32_16x16x32_bf16(wf[c],     a0, z, 0, 0, 0);
        z = __builtin_amdgcn_mfma_f32_16x16x32_bf16(wf[4 + c], a1, z, 0, 0, 0);
        f32x4 o;
        #pragma unroll
        for (int r = 0; r < 4; ++r)
            o[r] = z[r] * scale + rpv[c][r] + cpv[c][r];
        // nontemporal: don't let 131 MB of stores evict edges from L3
        __builtin_nontemporal_store(o, reinterpret_cast<f32x4*>(orow + c * 16));
    }
}

extern "C" void kernel_launch(void* const* d_in, const int* in_sizes, int n_in,
                              void* d_out, int out_size, void* d_ws, size_t ws_size,
                              hipStream_t stream) {
    const float* edges  = (const float*)d_in[0];
    const float* nodes  = (const float*)d_in[1];
    const float* g_node = (const float*)d_in[2];
    const float* g_edge = (const float*)d_in[3];
    const float* W      = (const float*)d_in[4];
    const float* bias   = (const float*)d_in[5];
    float* out = (float*)d_out;

    float*  rp  = (float*)d_ws;                 // 1024*64 f32 = 256 KB
    float*  cp  = rp + 1024 * DE;               // 256 KB
    __bf16* weg = (__bf16*)(cp + 1024 * DE);    // 8*64*8 bf16 = 8 KB

    prep_kernel<<<dim3(1025), dim3(64), 0, stream>>>(nodes, g_node, g_edge, W,
                                                     bias, rp, cp, weg);
    main_kernel<<<dim3(8192), dim3(256), 0, stream>>>(edges, rp, cp, weg, out);
}

// Round 4
// 69.265 us; speedup vs baseline: 1.0273x; 1.0014x over previous
//
#include <hip/hip_runtime.h>
#include <hip/hip_bf16.h>

#define DN 128
#define DE 64
#define NN 512

typedef __bf16 bf16x8 __attribute__((ext_vector_type(8)));
typedef float  f32x4  __attribute__((ext_vector_type(4)));

// -------- fused prep ---------------------------------------------------------
// blocks 0..1023: rms_norm(nodes)*g_node -> rp = nn@Wr + b, cp = nn@Wc
// block 1024:     pack g_edge[k]*We[k][col] into bf16 MFMA fragment order,
//                 using the COALESCING k-map shared with the main kernel's
//                 x loads: slot (kg, e) of K-half kh, quarter q=e>>2 ->
//                 k = kh*32 + q*16 + kg*4 + (e&3).
__global__ void prep_kernel(const float* __restrict__ nodes,
                            const float* __restrict__ g_node,
                            const float* __restrict__ g_edge,
                            const float* __restrict__ W,
                            const float* __restrict__ bias,
                            float* __restrict__ rp, float* __restrict__ cp,
                            __bf16* __restrict__ weg) {
    const int l = threadIdx.x;  // 0..63
    if (blockIdx.x == 1024) {
        const int kg = l >> 4;
        for (int kh = 0; kh < 2; ++kh)
            for (int ct = 0; ct < 4; ++ct) {
                const int f = kh * 4 + ct;
                #pragma unroll
                for (int e = 0; e < 8; ++e) {
                    const int k   = kh * 32 + (e >> 2) * 16 + kg * 4 + (e & 3);
                    const int col = ct * 16 + (l & 15);
                    weg[(f * 64 + l) * 8 + e] =
                        (__bf16)(g_edge[k] * W[(2 * DN + k) * DE + col]);
                }
            }
        return;
    }
    const int row = blockIdx.x;      // b*N + i
    __shared__ float nn[DN];

    float x0 = nodes[row * DN + l];
    float x1 = nodes[row * DN + l + 64];
    float ssq = x0 * x0 + x1 * x1;
    #pragma unroll
    for (int m = 1; m < 64; m <<= 1) ssq += __shfl_xor(ssq, m, 64);
    float scale = rsqrtf(ssq * (1.0f / DN) + 1.1920929e-7f);
    nn[l]      = x0 * scale * g_node[l];
    nn[l + 64] = x1 * scale * g_node[l + 64];
    __syncthreads();

    float accr = bias[l];
    float accc = 0.0f;
    #pragma unroll 4
    for (int d = 0; d < DN; ++d) {
        float nd = nn[d];
        accr += nd * W[d * DE + l];          // Wr = W[0:128]
        accc += nd * W[(DN + d) * DE + l];   // Wc = W[128:256]
    }
    rp[row * DE + l] = accr;
    cp[row * DE + l] = accc;
}

// -------- main: ONE 16x16 j-tile per wave, COALESCED edge loads -------------
// grid 8192 x 256. bid: row = bid>>3, j-chunk = (bid&7)*64; wave w -> +w*16.
// lane l: r16 = l&15 -> j within tile; kg = l>>4.
// Edge-load instr m (m=0..3) reads floats [m*16 + kg*4, +4) of row jt+r16:
// per instruction the 4 kg-lanes of a row cover a CONTIGUOUS 64 B span ->
// 16 x 64 B segments (was 64 x 16 B). k-map matches weg packing above.
__global__ __launch_bounds__(256) void main_kernel(
    const float* __restrict__ edges, const float* __restrict__ rp,
    const float* __restrict__ cp, const __bf16* __restrict__ weg,
    float* __restrict__ out) {
    const int bid  = blockIdx.x;       // 0..8191
    const int row  = bid >> 3;         // b*N + i
    const int w    = threadIdx.x >> 6;
    const int l    = threadIdx.x & 63;
    const int r16  = l & 15;
    const int kg   = l >> 4;
    const int jt   = (bid & 7) * 64 + w * 16;
    const int j    = jt + r16;         // this lane's edge row (j)
    const int bN   = (row >> 9) << 9;  // b*512

    // ---- issue ALL loads before any use ----
    const float* lp = edges + ((size_t)row * NN + j) * DE + kg * 4;
    f32x4 xA = *reinterpret_cast<const f32x4*>(lp);        // floats [kg*4, +4)
    f32x4 xB = *reinterpret_cast<const f32x4*>(lp + 16);   // [16+kg*4, +4)
    f32x4 xC = *reinterpret_cast<const f32x4*>(lp + 32);   // [32+kg*4, +4)
    f32x4 xD = *reinterpret_cast<const f32x4*>(lp + 48);   // [48+kg*4, +4)

    bf16x8 wf[8];
    #pragma unroll
    for (int f = 0; f < 8; ++f)
        wf[f] = *reinterpret_cast<const bf16x8*>(weg + (f * 64 + l) * 8);

    const float* cprow = cp + (size_t)(bN + j) * DE + kg * 4;
    f32x4 cpv[4];
    #pragma unroll
    for (int c = 0; c < 4; ++c)
        cpv[c] = *reinterpret_cast<const f32x4*>(cprow + c * 16);

    f32x4 rpv[4];
    #pragma unroll
    for (int c = 0; c < 4; ++c)
        rpv[c] = *reinterpret_cast<const f32x4*>(rp + row * DE + c * 16 + kg * 4);

    // ---- rms over this lane's row (row split across lanes l, l^16, l^32) ----
    float ssq = 0.0f;
    #pragma unroll
    for (int e = 0; e < 4; ++e)
        ssq += xA[e] * xA[e] + xB[e] * xB[e]
             + xC[e] * xC[e] + xD[e] * xD[e];
    ssq += __shfl_xor(ssq, 16, 64);
    ssq += __shfl_xor(ssq, 32, 64);
    const float scale = rsqrtf(ssq * (1.0f / DE) + 1.1920929e-7f);

    // fragments: a0 = K-half 0 (floats 0..31 via slots), a1 = K-half 1
    bf16x8 a0, a1;
    #pragma unroll
    for (int e = 0; e < 4; ++e) {
        a0[e]     = (__bf16)xA[e];   // k = kg*4+e
        a0[e + 4] = (__bf16)xB[e];   // k = 16+kg*4+e
        a1[e]     = (__bf16)xC[e];   // k = 32+kg*4+e
        a1[e + 4] = (__bf16)xD[e];   // k = 48+kg*4+e
    }

    float* orow = out + ((size_t)row * NN + j) * DE + kg * 4;
    #pragma unroll
    for (int c = 0; c < 4; ++c) {
        f32x4 z = {0.f, 0.f, 0.f, 0.f};
        z = __builtin_amdgcn_mfma_f32_16x16x32_bf16(wf[c],     a0, z, 0, 0, 0);
        z = __builtin_amdgcn_mfma_f32_16x16x32_bf16(wf[4 + c], a1, z, 0, 0, 0);
        f32x4 o;
        #pragma unroll
        for (int r = 0; r < 4; ++r)
            o[r] = z[r] * scale + rpv[c][r] + cpv[c][r];
        *reinterpret_cast<f32x4*>(orow + c * 16) = o;
    }
}

extern "C" void kernel_launch(void* const* d_in, const int* in_sizes, int n_in,
                              void* d_out, int out_size, void* d_ws, size_t ws_size,
                              hipStream_t stream) {
    const float* edges  = (const float*)d_in[0];
    const float* nodes  = (const float*)d_in[1];
    const float* g_node = (const float*)d_in[2];
    const float* g_edge = (const float*)d_in[3];
    const float* W      = (const float*)d_in[4];
    const float* bias   = (const float*)d_in[5];
    float* out = (float*)d_out;

    float*  rp  = (float*)d_ws;                 // 1024*64 f32 = 256 KB
    float*  cp  = rp + 1024 * DE;               // 256 KB
    __bf16* weg = (__bf16*)(cp + 1024 * DE);    // 8*64*8 bf16 = 8 KB

    prep_kernel<<<dim3(1025), dim3(64), 0, stream>>>(nodes, g_node, g_edge, W,
                                                     bias, rp, cp, weg);
    main_kernel<<<dim3(8192), dim3(256), 0, stream>>>(edges, rp, cp, weg, out);
}

// Round 5
// 61.035 us; speedup vs baseline: 1.1658x; 1.1348x over previous
//
#include <hip/hip_runtime.h>
#include <hip/hip_bf16.h>

#define DN 128
#define DE 64
#define NN 512

typedef __bf16 bf16x8 __attribute__((ext_vector_type(8)));
typedef float  f32x4  __attribute__((ext_vector_type(4)));

// -------- fused prep (unchanged from R4) ------------------------------------
// blocks 0..1023: rms_norm(nodes)*g_node -> rp = nn@Wr + b, cp = nn@Wc
// block 1024:     pack g_edge[k]*We[k][col] into bf16 MFMA fragment order,
//                 k-map: slot (kg, e), K-half kh, q=e>>2 ->
//                 k = kh*32 + q*16 + kg*4 + (e&3).
__global__ void prep_kernel(const float* __restrict__ nodes,
                            const float* __restrict__ g_node,
                            const float* __restrict__ g_edge,
                            const float* __restrict__ W,
                            const float* __restrict__ bias,
                            float* __restrict__ rp, float* __restrict__ cp,
                            __bf16* __restrict__ weg) {
    const int l = threadIdx.x;  // 0..63
    if (blockIdx.x == 1024) {
        const int kg = l >> 4;
        for (int kh = 0; kh < 2; ++kh)
            for (int ct = 0; ct < 4; ++ct) {
                const int f = kh * 4 + ct;
                #pragma unroll
                for (int e = 0; e < 8; ++e) {
                    const int k   = kh * 32 + (e >> 2) * 16 + kg * 4 + (e & 3);
                    const int col = ct * 16 + (l & 15);
                    weg[(f * 64 + l) * 8 + e] =
                        (__bf16)(g_edge[k] * W[(2 * DN + k) * DE + col]);
                }
            }
        return;
    }
    const int row = blockIdx.x;      // b*N + i
    __shared__ float nn[DN];

    float x0 = nodes[row * DN + l];
    float x1 = nodes[row * DN + l + 64];
    float ssq = x0 * x0 + x1 * x1;
    #pragma unroll
    for (int m = 1; m < 64; m <<= 1) ssq += __shfl_xor(ssq, m, 64);
    float scale = rsqrtf(ssq * (1.0f / DN) + 1.1920929e-7f);
    nn[l]      = x0 * scale * g_node[l];
    nn[l + 64] = x1 * scale * g_node[l + 64];
    __syncthreads();

    float accr = bias[l];
    float accc = 0.0f;
    #pragma unroll 4
    for (int d = 0; d < DN; ++d) {
        float nd = nn[d];
        accr += nd * W[d * DE + l];          // Wr = W[0:128]
        accc += nd * W[(DN + d) * DE + l];   // Wc = W[128:256]
    }
    rp[row * DE + l] = accr;
    cp[row * DE + l] = accc;
}

// -------- main: copy-identical VMEM pattern via LDS bounce ------------------
// grid 8192 x 256. block: 64-row j-tile (16 KB). row = bid>>3, jt0=(bid&7)*64.
// P1: global_load_lds, LDS linear (lane-contiguous), source inverse-swizzled
//     (chunk q = (C&15) ^ (r&15); XOR is an involution). Within an instr the
//     16 lanes of a row cover the row's full 256 B (permuted) -> full lines.
// P3: wave w computes tile rows [w*16, w*16+16): swizzled ds_read_b128
//     fragments (bank-balanced), ssq via 2 shfl_xor, 8 MFMA (layout = R4),
//     epilogue, swizzled ds_write_b128.
// P5: linear LDS read, full-line global stores (8 x 128 B lines per instr).
__global__ __launch_bounds__(256) void main_kernel(
    const float* __restrict__ edges, const float* __restrict__ rp,
    const float* __restrict__ cp, const __bf16* __restrict__ weg,
    float* __restrict__ out) {
    __shared__ float lds[4096];            // 16 KB tile
    const int bid = blockIdx.x;            // 0..8191
    const int row = bid >> 3;              // b*N + i
    const int t   = threadIdx.x;           // 0..255
    const int w   = t >> 6;
    const int l   = t & 63;
    const int r16 = l & 15;
    const int kg  = l >> 4;
    const int jt0 = (bid & 7) * 64;        // tile j base (64 rows)
    const int bN  = (row >> 9) << 9;       // b*512

    const float* tile = edges + ((size_t)row * NN + jt0) * DE;

    // ---- P1: global -> LDS (direct), linear dest + inverse-swz source ----
    #pragma unroll
    for (int i = 0; i < 4; ++i) {
        const int C = i * 256 + t;          // chunk this lane fills
        const int r = C >> 4;               // tile-local row
        const int q = (C & 15) ^ (r & 15);  // source chunk within row
        __builtin_amdgcn_global_load_lds(
            (const __attribute__((address_space(1))) void*)(tile + r * DE + q * 4),
            (__attribute__((address_space(3))) void*)(&lds[(i * 256 + w * 64) * 4]),
            16, 0, 0);
    }

    // ---- other operands to regs (L1/L2-hot) ----
    bf16x8 wf[8];
    #pragma unroll
    for (int f = 0; f < 8; ++f)
        wf[f] = *reinterpret_cast<const bf16x8*>(weg + (f * 64 + l) * 8);

    const int j = jt0 + w * 16 + r16;       // this lane's global j
    const float* cprow = cp + (size_t)(bN + j) * DE + kg * 4;
    f32x4 cpv[4];
    #pragma unroll
    for (int c = 0; c < 4; ++c)
        cpv[c] = *reinterpret_cast<const f32x4*>(cprow + c * 16);

    f32x4 rpv[4];
    #pragma unroll
    for (int c = 0; c < 4; ++c)
        rpv[c] = *reinterpret_cast<const f32x4*>(rp + row * DE + c * 16 + kg * 4);

    __syncthreads();   // all LDS fills complete (barrier drains vmcnt)

    // ---- P3: fragments from LDS (swizzled reads) ----
    const int R = w * 16 + r16;             // tile-local row this lane owns
    f32x4 x[4];
    #pragma unroll
    for (int m = 0; m < 4; ++m) {
        const int q = (m * 4 + kg) ^ r16;
        x[m] = *reinterpret_cast<const f32x4*>(&lds[R * 64 + q * 4]);
    }

    float ssq = 0.0f;
    #pragma unroll
    for (int m = 0; m < 4; ++m)
        #pragma unroll
        for (int e = 0; e < 4; ++e) ssq += x[m][e] * x[m][e];
    ssq += __shfl_xor(ssq, 16, 64);
    ssq += __shfl_xor(ssq, 32, 64);
    const float scale = rsqrtf(ssq * (1.0f / DE) + 1.1920929e-7f);

    bf16x8 a0, a1;
    #pragma unroll
    for (int e = 0; e < 4; ++e) {
        a0[e]     = (__bf16)x[0][e];   // k = kg*4+e
        a0[e + 4] = (__bf16)x[1][e];   // k = 16+kg*4+e
        a1[e]     = (__bf16)x[2][e];   // k = 32+kg*4+e
        a1[e + 4] = (__bf16)x[3][e];   // k = 48+kg*4+e
    }

    #pragma unroll
    for (int c = 0; c < 4; ++c) {
        f32x4 z = {0.f, 0.f, 0.f, 0.f};
        z = __builtin_amdgcn_mfma_f32_16x16x32_bf16(wf[c],     a0, z, 0, 0, 0);
        z = __builtin_amdgcn_mfma_f32_16x16x32_bf16(wf[4 + c], a1, z, 0, 0, 0);
        f32x4 o;
        #pragma unroll
        for (int r = 0; r < 4; ++r)
            o[r] = z[r] * scale + rpv[c][r] + cpv[c][r];
        const int qo = (c * 4 + kg) ^ r16;  // swizzled LDS write-back
        *reinterpret_cast<f32x4*>(&lds[R * 64 + qo * 4]) = o;
    }

    __syncthreads();   // all epilogue writes visible

    // ---- P5: LDS linear -> global, full-line stores ----
    float* otile = out + ((size_t)row * NN + jt0) * DE;
    #pragma unroll
    for (int i = 0; i < 4; ++i) {
        const int C = i * 256 + t;
        const int r = C >> 4;
        const int q = (C & 15) ^ (r & 15);
        f32x4 v = *reinterpret_cast<const f32x4*>(&lds[C * 4]);
        *reinterpret_cast<f32x4*>(otile + r * DE + q * 4) = v;
    }
}

extern "C" void kernel_launch(void* const* d_in, const int* in_sizes, int n_in,
                              void* d_out, int out_size, void* d_ws, size_t ws_size,
                              hipStream_t stream) {
    const float* edges  = (const float*)d_in[0];
    const float* nodes  = (const float*)d_in[1];
    const float* g_node = (const float*)d_in[2];
    const float* g_edge = (const float*)d_in[3];
    const float* W      = (const float*)d_in[4];
    const float* bias   = (const float*)d_in[5];
    float* out = (float*)d_out;

    float*  rp  = (float*)d_ws;                 // 1024*64 f32 = 256 KB
    float*  cp  = rp + 1024 * DE;               // 256 KB
    __bf16* weg = (__bf16*)(cp + 1024 * DE);    // 8*64*8 bf16 = 8 KB

    prep_kernel<<<dim3(1025), dim3(64), 0, stream>>>(nodes, g_node, g_edge, W,
                                                     bias, rp, cp, weg);
    main_kernel<<<dim3(8192), dim3(256), 0, stream>>>(edges, rp, cp, weg, out);
}